// Round 4
// baseline (692.056 us; speedup 1.0000x reference)
//
#include <hip/hip_runtime.h>

#define HW 96
#define NPIX 9216      // 96*96
#define NCH 128
#define NB 16
#define HP 98          // haloed plane dim (coords -1..96)

// ---------------- channel mix: mixed[b,c,p] = sum_i lin[c,i] * x[b,i,p] ----------------
// No-LDS GEMM. R9 retile: block = 256 thr (4 waves), wave = 8 ch (lin wave-uniform
// -> s_load into SGPRs), tile = 288 px x 32 ch. Grid = 32 px-tiles x 4 ch-blocks
// x 16 b = 2048 blocks = EXACTLY 8 blocks/CU -> 32 waves/CU, ONE balanced round.
// Rationale (R5/R7 post-mortems): total thread count at 2px/16ch is 1.125x machine
// capacity INVARIANT of tiling -> either a tail round (R5, 70us) or 75% fill
// (R7, 80us: <8 waves/SIMD exposes memory latency). Fractional px/thread (4.5)
// hits capacity exactly: 4 px as two coalesced float2 streams in the main loop
// + a 32-lane strip phase for the half px. Issue eff = 4.5/5 = 90%.
// Per-SIMD VALU work ~34us -> predict ~40-45us/dispatch (FMA floor 30.7us).
// R6 lesson: NO manual ping-pong; compiler pipelines the simple batch loop.
template<int K>
__global__ __launch_bounds__(256, 8) void mix_kernel(const float* __restrict__ x,
                                                     const float* __restrict__ lin,
                                                     float* __restrict__ mixed) {
    const int b    = blockIdx.y;
    const int bx   = blockIdx.x;              // 0..127
    const int tile = bx >> 2;                 // 0..31  -> pixel tile
    const int cb   = bx & 3;                  // 0..3   -> channel block
    const int lane = threadIdx.x & 63;
    const int c0   = __builtin_amdgcn_readfirstlane(cb * 32 + (threadIdx.x >> 6) * 8);
    const int pbase = tile * 288;
    const float* xb = x + (size_t)b * K * NPIX + pbase;
    const float* lr = lin + c0 * K;

    float2 accA[8], accB[8];
    #pragma unroll
    for (int c = 0; c < 8; ++c) { accA[c] = float2{0.f, 0.f}; accB[c] = float2{0.f, 0.f}; }

    for (int k0 = 0; k0 < K; k0 += 4) {
        float2 xa[4], xv[4];
        #pragma unroll
        for (int j = 0; j < 4; ++j) {
            const float* xp = xb + (size_t)(k0 + j) * NPIX;
            xa[j] = *(const float2*)&xp[2 * lane];          // px pbase+2l, +2l+1
            xv[j] = *(const float2*)&xp[128 + 2 * lane];    // px pbase+128+2l, ...
        }
        #pragma unroll
        for (int c = 0; c < 8; ++c) {
            const float* lc = lr + c * K + k0;              // wave-uniform -> s_load
            #pragma unroll
            for (int j = 0; j < 4; ++j) {
                accA[c].x = fmaf(lc[j], xa[j].x, accA[c].x);
                accA[c].y = fmaf(lc[j], xa[j].y, accA[c].y);
                accB[c].x = fmaf(lc[j], xv[j].x, accB[c].x);
                accB[c].y = fmaf(lc[j], xv[j].y, accB[c].y);
            }
        }
    }
    float* ob = mixed + (size_t)b * NCH * NPIX + pbase;
    #pragma unroll
    for (int c = 0; c < 8; ++c) {
        float* op = ob + (size_t)(c0 + c) * NPIX;
        *(float2*)&op[2 * lane]       = accA[c];
        *(float2*)&op[128 + 2 * lane] = accB[c];
    }
    // ---- strip phase: px pbase+256..pbase+287, lanes 0..31 (the 0.5 px/lane) ----
    if (lane < 32) {
        float accC[8];
        #pragma unroll
        for (int c = 0; c < 8; ++c) accC[c] = 0.f;
        for (int k0 = 0; k0 < K; k0 += 8) {
            float xc[8];
            #pragma unroll
            for (int j = 0; j < 8; ++j)
                xc[j] = xb[(size_t)(k0 + j) * NPIX + 256 + lane];
            #pragma unroll
            for (int c = 0; c < 8; ++c) {
                const float* lc = lr + c * K + k0;
                #pragma unroll
                for (int j = 0; j < 8; ++j)
                    accC[c] = fmaf(lc[j], xc[j], accC[c]);
            }
        }
        #pragma unroll
        for (int c = 0; c < 8; ++c)
            ob[(size_t)(c0 + c) * NPIX + 256 + lane] = accC[c];
    }
}

__device__ inline float clamp01(float z) { return fminf(fmaxf(z, 0.f), 1.f); }

// ---------------- bilinear affine sample (zero-halo LDS plane) ----------------
// Plane staged into LDS with a 1px zero border (coords -1..96). ix clamped to
// [-1,96]: every out-of-range tap then reads a zero cell with the correct
// weight, eliminating all validity masks. Box-sample-of-ones factorizes:
// bw = min(clamp01(bx+1), clamp01(96-bx)) * (same in y). 2-lerp form = 6 FMA.
// 512 threads: LDS (38.4 KB) allows 4 blocks/CU -> 32 waves/CU; grid 2048 =
// exactly 2 balanced rounds of 4 blocks/CU. (R6 evidence: 384->512 thr helped.)
template<bool RES, bool POOL>
__global__ __launch_bounds__(512) void sample_kernel(const float* __restrict__ mixed,
                                                     const float* __restrict__ geo,
                                                     const float* __restrict__ box,
                                                     float* __restrict__ out,
                                                     float* __restrict__ pooled) {
    __shared__ float m[HP * HP];           // 38.4 KB -> 4 blocks/CU, 32 waves/CU
    const int c = blockIdx.x;
    const int b = blockIdx.y;
    const int t = threadIdx.x;
    // zero only the halo border (interior is fully overwritten by the fill)
    if (t < HP) {                           // top & bottom rows
        m[t] = 0.f;
        m[(HP - 1) * HP + t] = 0.f;
    } else if (t < HP + 96) {               // left & right columns (rows 1..96)
        const int h = t - HP + 1;
        m[h * HP] = 0.f;
        m[h * HP + HP - 1] = 0.f;
    }
    const float* src = mixed + ((size_t)b * NCH + c) * NPIX;
    #pragma unroll
    for (int r = 0; r < NPIX / 512; ++r) {
        const int idx = r * 512 + t;
        const int h = idx / 96, w = idx - (idx / 96) * 96;
        m[(h + 1) * HP + (w + 1)] = src[idx];
    }
    const float* gth = geo + c * 6;
    const float* bth = box + c * 6;
    const float g0 = gth[0], g1 = gth[1], g3 = gth[3], g4 = gth[4];
    const float gcx = 48.f * gth[2] - 47.5f * (g0 + g1) + 47.5f;
    const float gcy = 48.f * gth[5] - 47.5f * (g3 + g4) + 47.5f;
    const float b0 = bth[0], b1 = bth[1], b3 = bth[3], b4 = bth[4];
    const float bcx = 48.f * bth[2] - 47.5f * (b0 + b1) + 47.5f;
    const float bcy = 48.f * bth[5] - 47.5f * (b3 + b4) + 47.5f;
    float* o = out + ((size_t)b * NCH + c) * NPIX;
    __syncthreads();
    float psum = 0.f;
    #pragma unroll 6
    for (int r = 0; r < NPIX / 512; ++r) {
        const int p = r * 512 + t;
        const int h = p / 96, w = p - (p / 96) * 96;
        const float fw = (float)w, fh = (float)h;
        float ix = fmaf(g0, fw, fmaf(g1, fh, gcx));
        float iy = fmaf(g3, fw, fmaf(g4, fh, gcy));
        ix = fminf(fmaxf(ix, -1.f), 96.f);
        iy = fminf(fmaxf(iy, -1.f), 96.f);
        const float x0f = floorf(ix), y0f = floorf(iy);
        const float fx = ix - x0f, fy = iy - y0f;
        const int base = ((int)y0f + 1) * HP + ((int)x0f + 1);
        const float m00 = m[base],      m01 = m[base + 1];
        const float m10 = m[base + HP], m11 = m[base + HP + 1];
        const float mx0 = fmaf(fx, m01 - m00, m00);
        const float mx1 = fmaf(fx, m11 - m10, m10);
        float v = fmaf(fy, mx1 - mx0, mx0);
        const float bx = fmaf(b0, fw, fmaf(b1, fh, bcx));
        const float by = fmaf(b3, fw, fmaf(b4, fh, bcy));
        const float Xs = fminf(clamp01(bx + 1.f), clamp01(96.f - bx));
        const float Ys = fminf(clamp01(by + 1.f), clamp01(96.f - by));
        v *= Xs * Ys;
        if (RES) v += o[p];
        o[p] = v;
        if (POOL) psum += v;
    }
    if (POOL) {
        #pragma unroll
        for (int off = 32; off > 0; off >>= 1) psum += __shfl_down(psum, off, 64);
        __shared__ float red[8];
        if ((t & 63) == 0) red[t >> 6] = psum;
        __syncthreads();
        if (t == 0) {
            float s = 0.f;
            #pragma unroll
            for (int i = 0; i < 8; ++i) s += red[i];
            pooled[b * NCH + c] = s * (1.f / (float)NPIX);
        }
    }
}

// ---------------- mean pool (fallback when ws has no room for pooled) ----------------
__global__ __launch_bounds__(256) void pool_kernel(const float* __restrict__ feat,
                                                   float* __restrict__ pooled) {
    const int bc = blockIdx.x;           // b*128 + c
    const float4* f = (const float4*)(feat + (size_t)bc * NPIX);
    float s = 0.f;
    for (int i = threadIdx.x; i < NPIX / 4; i += 256) {
        const float4 v = f[i];
        s += (v.x + v.y) + (v.z + v.w);
    }
    #pragma unroll
    for (int off = 32; off > 0; off >>= 1) s += __shfl_down(s, off, 64);
    __shared__ float red[4];
    if ((threadIdx.x & 63) == 0) red[threadIdx.x >> 6] = s;
    __syncthreads();
    if (threadIdx.x == 0)
        pooled[bc] = (red[0] + red[1] + red[2] + red[3]) * (1.f / (float)NPIX);
}

// ---------------- dense: logits[b,n] = pooled[b,:] . W[n,:] + bias[n] ----------------
__global__ __launch_bounds__(256) void dense_kernel(const float* __restrict__ pooled,
                                                    const float* __restrict__ Wt,
                                                    const float* __restrict__ bias,
                                                    float* __restrict__ out) {
    const int idx = blockIdx.x * 256 + threadIdx.x;
    if (idx >= NB * 1000) return;
    const int b = idx / 1000, n = idx - b * 1000;
    float acc = bias[n];
    const float* p = pooled + b * NCH;
    const float* wr = Wt + n * NCH;
    #pragma unroll 4
    for (int c = 0; c < NCH; ++c) acc = fmaf(p[c], wr[c], acc);
    out[idx] = acc;
}

extern "C" void kernel_launch(void* const* d_in, const int* in_sizes, int n_in,
                              void* d_out, int out_size, void* d_ws, size_t ws_size,
                              hipStream_t stream) {
    const float* x       = (const float*)d_in[0];   // [16,64,96,96]
    const float* in_geo  = (const float*)d_in[1];   // [128,2,3]
    const float* in_box  = (const float*)d_in[2];   // [128,2,3]
    const float* in_lin  = (const float*)d_in[3];   // [128,64]
    const float* lay_geo = (const float*)d_in[4];   // [4,128,2,3]
    const float* lay_box = (const float*)d_in[5];   // [4,128,2,3]
    const float* lay_lin = (const float*)d_in[6];   // [4,128,128]
    const float* dense_w = (const float*)d_in[7];   // [1000,128]
    const float* dense_b = (const float*)d_in[8];   // [1000]

    float* out  = (float*)d_out;
    float* feat = out + NB * 1000;                  // [16,128,96,96] lives in d_out
    float* mixed = (float*)d_ws;                    // 75.5 MB scratch

    const size_t mixedFloats = (size_t)NB * NCH * NPIX;
    const bool fusedPool = ws_size >= (mixedFloats + NB * NCH) * sizeof(float);
    float* pooled = fusedPool ? (float*)d_ws + mixedFloats : (float*)d_ws;

    const dim3 mixGrid(128, NB);                    // 32 px-tiles x 4 ch-blocks, 16 b = 2048 blocks
    const dim3 smpGrid(NCH, NB);

    mix_kernel<64><<<mixGrid, 256, 0, stream>>>(x, in_lin, mixed);
    sample_kernel<false, false><<<smpGrid, 512, 0, stream>>>(mixed, in_geo, in_box, feat, pooled);
    for (int i = 0; i < 3; ++i) {
        mix_kernel<128><<<mixGrid, 256, 0, stream>>>(feat, lay_lin + i * NCH * NCH, mixed);
        sample_kernel<true, false><<<smpGrid, 512, 0, stream>>>(mixed, lay_geo + i * NCH * 6,
                                                                lay_box + i * NCH * 6, feat, pooled);
    }
    mix_kernel<128><<<mixGrid, 256, 0, stream>>>(feat, lay_lin + 3 * NCH * NCH, mixed);
    if (fusedPool) {
        sample_kernel<true, true><<<smpGrid, 512, 0, stream>>>(mixed, lay_geo + 3 * NCH * 6,
                                                               lay_box + 3 * NCH * 6, feat, pooled);
    } else {
        sample_kernel<true, false><<<smpGrid, 512, 0, stream>>>(mixed, lay_geo + 3 * NCH * 6,
                                                                lay_box + 3 * NCH * 6, feat, pooled);
        pool_kernel<<<NB * NCH, 256, 0, stream>>>(feat, pooled);
    }
    dense_kernel<<<(NB * 1000 + 255) / 256, 256, 0, stream>>>(pooled, dense_w, dense_b, out);
}